// Round 12
// baseline (854.418 us; speedup 1.0000x reference)
//
#include <hip/hip_runtime.h>
#include <hip/hip_bf16.h>

// Problem constants (from reference)
#define N_NODES 100000
#define N_EDGES 1600000
#define HID 128
#define OUTC 64
#define NLAYERS 3

#define M_PAD 100032            // 64-row-tile padded M (1563 * 64)
#define SCAN_N (2 * N_NODES)    // joint scan over [row_counts | col_counts]
#define SCAN_B 1024
#define SCAN_NB ((SCAN_N + SCAN_B - 1) / SCAN_B)  // 196

#define GEMM_BLOCKS (M_PAD / 64)                  // 1563
#define EDGE_BLOCKS ((N_EDGES + 255) / 256)       // 6250
#define PAIR_BLOCKS ((N_EDGES / 2 + 255) / 256)   // 3125

typedef __attribute__((ext_vector_type(8))) short short8;
typedef __attribute__((ext_vector_type(4))) float f32x4;
typedef __attribute__((ext_vector_type(2))) float f32x2;

__device__ __forceinline__ unsigned short f2b(float f) {
  return __builtin_bit_cast(unsigned short, __float2bfloat16(f));
}
__device__ __forceinline__ float blo(unsigned int u) {  // low bf16 -> f32
  return __builtin_bit_cast(float, u << 16);
}
__device__ __forceinline__ float bhi(unsigned int u) {  // high bf16 -> f32
  return __builtin_bit_cast(float, u & 0xffff0000u);
}

// ---------------------------------------------------------------------------
// Cast + transpose all weights into Wt[n][k] bf16.  All matrices have K=128.
// blocks: [0,128) W_in | [128,512) W_convs | [512,576) W_fc
// ---------------------------------------------------------------------------
__global__ __launch_bounds__(128) void cast_w_kernel(
    const float* __restrict__ W_in, const float* __restrict__ W_convs,
    const float* __restrict__ W_fc, unsigned short* __restrict__ wt) {
  const int b = blockIdx.x;
  const int k = threadIdx.x;
  const float* src;
  unsigned short* dst;
  int n, N;
  if (b < 128) {
    n = b; N = 128; src = W_in; dst = wt + n * 128;
  } else if (b < 512) {
    const int l = (b - 128) >> 7;
    n = (b - 128) & 127; N = 128;
    src = W_convs + (size_t)l * 16384;
    dst = wt + 16384 * (1 + l) + n * 128;
  } else {
    n = b - 512; N = 64; src = W_fc; dst = wt + 65536 + n * 128;
  }
  dst[k] = f2b(src[k * N + n]);
}

// ---------------------------------------------------------------------------
// MFMA GEMM: Y[m][n] = sum_k A[m][k] * Wt[n][k]  (K=128, bf16 MFMA, f32 acc)
// Block = 4 waves x 16 rows = 64 rows.  Wave computes 16 x (NT*16) tile.
// MODE 0: A = f32 src (row-guarded, converted in-reg); write bf16 Yb (N=128)
// MODE 1: A = bf16 Xb;                  write bf16 Yb (N=128)
// MODE 2: A = bf16 Xb; write f32 Y + bias, store-guarded (N=64)  [final fc]
// ---------------------------------------------------------------------------
template <int MODE>
__global__ __launch_bounds__(256) void gemm_mfma_kernel(
    const float* __restrict__ Xf, const unsigned short* __restrict__ Xb,
    const unsigned short* __restrict__ Wt, const float* __restrict__ bias,
    float* __restrict__ Y, unsigned short* __restrict__ Yb) {
  constexpr int NT = (MODE == 2) ? 4 : 8;  // n-tiles of 16
  const int wave = threadIdx.x >> 6;
  const int lane = threadIdx.x & 63;
  const int row0 = blockIdx.x * 64 + wave * 16;
  const int lm = lane & 15;        // m (A) / n (B) index within tile
  const int lk = (lane >> 4) * 8;  // k-group offset

  f32x4 acc[NT];
#pragma unroll
  for (int t = 0; t < NT; ++t) acc[t] = {0.f, 0.f, 0.f, 0.f};

  const int arow = row0 + lm;
#pragma unroll
  for (int ki = 0; ki < 4; ++ki) {
    short8 a;
    if (MODE == 0) {
      float av[8];
      const bool ok = arow < N_NODES;
#pragma unroll
      for (int j = 0; j < 8; ++j)
        av[j] = ok ? Xf[(size_t)arow * 128 + ki * 32 + lk + j] : 0.f;
#pragma unroll
      for (int j = 0; j < 8; ++j)
        a[j] = (short)f2b(av[j]);
    } else {
      a = *reinterpret_cast<const short8*>(Xb + (size_t)arow * 128 + ki * 32 + lk);
    }
#pragma unroll
    for (int t = 0; t < NT; ++t) {
      const short8 b =
          *reinterpret_cast<const short8*>(Wt + (t * 16 + lm) * 128 + ki * 32 + lk);
      acc[t] = __builtin_amdgcn_mfma_f32_16x16x32_bf16(a, b, acc[t], 0, 0, 0);
    }
  }

  const int orow = row0 + (lane >> 4) * 4;  // + r
#pragma unroll
  for (int t = 0; t < NT; ++t) {
#pragma unroll
    for (int r = 0; r < 4; ++r) {
      const int rr = orow + r;
      const int cc = t * 16 + lm;
      const float v = acc[t][r];
      if (MODE == 2) {
        if (rr < N_NODES) Y[(size_t)rr * OUTC + cc] = v + bias[cc];
      } else {
        Yb[(size_t)rr * 128 + cc] = f2b(v);
      }
    }
  }
}

// ---------------------------------------------------------------------------
// CSR build step 1: per-node degree counts + per-edge ranks.  Lean kernel
// (4 VGPR, max occupancy) — atomic-latency-bound, do NOT fuse compute in.
// ---------------------------------------------------------------------------
__global__ __launch_bounds__(256) void count_kernel(
    const int* __restrict__ row, const int* __restrict__ col,
    int* __restrict__ counts, unsigned int* __restrict__ ranks) {
  const int e = blockIdx.x * 256 + threadIdx.x;
  if (e >= N_EDGES) return;
  const int pr = atomicAdd(counts + row[e], 1);
  const int pc = atomicAdd(counts + N_NODES + col[e], 1);
  ranks[e] = (unsigned)pr | ((unsigned)pc << 16);
}

__global__ __launch_bounds__(SCAN_B) void scan1_kernel(
    const int* __restrict__ counts, int* __restrict__ incl,
    int* __restrict__ bsum) {
  __shared__ int tmp[SCAN_B];
  const int i = blockIdx.x * SCAN_B + threadIdx.x;
  tmp[threadIdx.x] = (i < SCAN_N) ? counts[i] : 0;
  __syncthreads();
  for (int d = 1; d < SCAN_B; d <<= 1) {
    int t = (threadIdx.x >= d) ? tmp[threadIdx.x - d] : 0;
    __syncthreads();
    tmp[threadIdx.x] += t;
    __syncthreads();
  }
  if (i < SCAN_N) incl[i] = tmp[threadIdx.x];
  if (threadIdx.x == SCAN_B - 1) bsum[blockIdx.x] = tmp[SCAN_B - 1];
}

__global__ __launch_bounds__(256) void scan2_kernel(int* __restrict__ bsum) {
  __shared__ int tmp[256];
  tmp[threadIdx.x] = (threadIdx.x < SCAN_NB) ? bsum[threadIdx.x] : 0;
  __syncthreads();
  for (int d = 1; d < 256; d <<= 1) {
    int t = (threadIdx.x >= d) ? tmp[threadIdx.x - d] : 0;
    __syncthreads();
    tmp[threadIdx.x] += t;
    __syncthreads();
  }
  if (threadIdx.x < SCAN_NB) bsum[threadIdx.x] = tmp[threadIdx.x];
}

// Scan step C: seg[i] = {exclusive start, count} (int2, one 8B load for users)
__global__ __launch_bounds__(SCAN_B) void scan3_kernel(
    const int* __restrict__ counts, const int* __restrict__ incl,
    const int* __restrict__ bsum, int2* __restrict__ seg) {
  const int i = blockIdx.x * SCAN_B + threadIdx.x;
  if (i >= SCAN_N) return;
  const int c = counts[i];
  const int v = incl[i] + (blockIdx.x > 0 ? bsum[blockIdx.x - 1] : 0);
  seg[i] = make_int2(v - c, c);
}

// ---------------------------------------------------------------------------
// CSR build step 2: fill adjacency — atomic-free; 2 edges per thread.
// adj[pos in [0,E)]   = col[e]  (neighbors of row-node, for tau)
// adj[pos in [E,2E)]  = row[e]  (sources of col-node, for aggregation)
// ---------------------------------------------------------------------------
__global__ __launch_bounds__(256) void fill_kernel(
    const int* __restrict__ row, const int* __restrict__ col,
    const unsigned int* __restrict__ ranks, const int2* __restrict__ seg,
    int* __restrict__ adj) {
  const int p = blockIdx.x * 256 + threadIdx.x;  // pair index
  if (p * 2 >= N_EDGES) return;
  const int2 r2 = reinterpret_cast<const int2*>(row)[p];
  const int2 c2 = reinterpret_cast<const int2*>(col)[p];
  const uint2 u2 = reinterpret_cast<const uint2*>(ranks)[p];
  adj[seg[r2.x].x + (int)(u2.x & 0xffffu)] = c2.x;
  adj[seg[N_NODES + c2.x].x + (int)(u2.x >> 16)] = r2.x;
  adj[seg[r2.y].x + (int)(u2.y & 0xffffu)] = c2.y;
  adj[seg[N_NODES + c2.y].x + (int)(u2.y >> 16)] = r2.y;
}

// ---------------------------------------------------------------------------
// Quantize h rows to int8 with per-row scale.  One wave per node.
//   scl[n] = rowmax/127;  h8[n] = round(h/scl) packed 2 int8 per ushort.
// ---------------------------------------------------------------------------
__global__ __launch_bounds__(256) void quant_h_kernel(
    const unsigned int* __restrict__ hb, unsigned short* __restrict__ h8,
    float* __restrict__ scl) {
  const int g = blockIdx.x * 256 + threadIdx.x;
  const int n = g >> 6;
  if (n >= N_NODES) return;
  const int lane = g & 63;
  const unsigned int p = hb[(size_t)n * 64 + lane];
  const float x0 = blo(p), x1 = bhi(p);
  float m = fmaxf(fabsf(x0), fabsf(x1));
  m = fmaxf(m, __shfl_xor(m, 1));
  m = fmaxf(m, __shfl_xor(m, 2));
  m = fmaxf(m, __shfl_xor(m, 4));
  m = fmaxf(m, __shfl_xor(m, 8));
  m = fmaxf(m, __shfl_xor(m, 16));
  m = fmaxf(m, __shfl_xor(m, 32));
  const float inv = (m > 0.f) ? 127.0f / m : 0.f;
  if (lane == 0) scl[n] = m * (1.0f / 127.0f);
  const int q0 = __float2int_rn(x0 * inv);
  const int q1 = __float2int_rn(x1 * inv);
  h8[(size_t)n * 64 + lane] =
      (unsigned short)((q0 & 0xff) | ((q1 & 0xff) << 8));
}

// ---------------------------------------------------------------------------
// Pack source-id + bf16(scale) into one word per agg edge:
//   adjs[i] = src | (bf16_bits(scl[src]) << 17)    (src < 2^17, scale >= 0)
// Isolated kernel: the random scl reads hit a 400 KB L2-hot array; aggregate
// then needs NO separate per-edge scale access (saves 1 L3 sector per edge).
// ---------------------------------------------------------------------------
__global__ __launch_bounds__(256) void edge_scl_kernel(
    const int* __restrict__ adj_agg, const float* __restrict__ scl,
    unsigned int* __restrict__ adjs) {
  const int i = blockIdx.x * 256 + threadIdx.x;
  if (i >= N_EDGES) return;
  const int id = adj_agg[i];
  const unsigned int sb = (unsigned int)f2b(scl[id]);  // sign bit = 0
  adjs[i] = (unsigned int)id | (sb << 17);
}

// ---------------------------------------------------------------------------
// Aggregate (gather, int8 + packed scale):
//   xnew[n] = relu(sum_{e: col=n} scl[s]*h8[s] + b)
// One wave per node; lane holds dims [2l, 2l+1].  One coalesced adjs word
// per edge carries id+scale; gather is a 128B int8 row (2 sectors).
// Writes bf16 (gate / next GEMM) AND fp8 e4m3 (tau neighbor gather).
// ---------------------------------------------------------------------------
__global__ __launch_bounds__(256) void aggregate_kernel(
    const unsigned short* __restrict__ h8, const unsigned int* __restrict__ adjs,
    const int2* __restrict__ seg, const float* __restrict__ b,
    unsigned int* __restrict__ xnewb, unsigned short* __restrict__ xnew8) {
  const int g = blockIdx.x * 256 + threadIdx.x;
  const int n = g >> 6;
  if (n >= N_NODES) return;
  const int lane = g & 63;
  const int2 sg = seg[N_NODES + n];
  const int start = sg.x - N_EDGES;  // agg segment positions live in [E,2E)
  const int end = start + sg.y;

  float ax[8], ay[8];
#pragma unroll
  for (int j = 0; j < 8; ++j) { ax[j] = 0.f; ay[j] = 0.f; }
  int i = start;
  for (; i + 7 < end; i += 8) {
    unsigned int w[8];
    unsigned int u[8];
#pragma unroll
    for (int j = 0; j < 8; ++j) w[j] = adjs[i + j];
#pragma unroll
    for (int j = 0; j < 8; ++j)
      u[j] = h8[(size_t)(w[j] & 0x1ffffu) * 64 + lane];
#pragma unroll
    for (int j = 0; j < 8; ++j) {
      const float s = __builtin_bit_cast(float, (w[j] & 0xfffe0000u) >> 1);
      ax[j] += (float)(int)(signed char)(u[j] & 0xff) * s;
      ay[j] += (float)((int)(short)(unsigned short)u[j] >> 8) * s;
    }
  }
  for (; i < end; ++i) {
    const unsigned int w0 = adjs[i];
    const unsigned int u0 = h8[(size_t)(w0 & 0x1ffffu) * 64 + lane];
    const float s0 = __builtin_bit_cast(float, (w0 & 0xfffe0000u) >> 1);
    ax[0] += (float)(int)(signed char)(u0 & 0xff) * s0;
    ay[0] += (float)((int)(short)(unsigned short)u0 >> 8) * s0;
  }
#pragma unroll
  for (int j = 4; j < 8; ++j) { ax[j - 4] += ax[j]; ay[j - 4] += ay[j]; }
  const float2 bb = *reinterpret_cast<const float2*>(b + lane * 2);
  const float ox = fmaxf(((ax[0] + ax[1]) + (ax[2] + ax[3])) + bb.x, 0.f);
  const float oy = fmaxf(((ay[0] + ay[1]) + (ay[2] + ay[3])) + bb.y, 0.f);
  xnewb[(size_t)n * 64 + lane] = (unsigned)f2b(ox) | ((unsigned)f2b(oy) << 16);
  const unsigned int p8 = __builtin_amdgcn_cvt_pk_fp8_f32(ox, oy, 0u, false);
  xnew8[(size_t)n * 64 + lane] = (unsigned short)(p8 & 0xffffu);
}

// ---------------------------------------------------------------------------
// Tau + gated update, fused.  Neighbor rows gathered as fp8 e4m3 (tau is
// tanh-saturated -> quantization noise is annihilated).  One wave per node:
//   s   = sum_{e: row=n} ||xnew[n] - xnew[col[e]]||^2
//   tau = tanh(s / (deg + 1e-10))
//   x[n] = (1-tau)*x[n] + tau*xnew[n]   (bf16 x)
// ---------------------------------------------------------------------------
__global__ __launch_bounds__(256) void tau_update_kernel(
    const unsigned int* __restrict__ xnewb, const unsigned short* __restrict__ xnew8,
    const int2* __restrict__ seg, const int* __restrict__ adj,
    unsigned int* __restrict__ x) {
  const int g = blockIdx.x * 256 + threadIdx.x;
  const int n = g >> 6;
  if (n >= N_NODES) return;
  const int lane = g & 63;
  const int2 sg = seg[n];
  const int start = sg.x;
  const int cnt = sg.y;
  const int end = start + cnt;

  const unsigned int mp = xnewb[(size_t)n * 64 + lane];
  const float mx = blo(mp), my = bhi(mp);

  float s0 = 0.f, s1 = 0.f, s2 = 0.f, s3 = 0.f;
  int i = start;
  for (; i + 3 < end; i += 4) {
    const unsigned int u0 = xnew8[(size_t)adj[i] * 64 + lane];
    const unsigned int u1 = xnew8[(size_t)adj[i + 1] * 64 + lane];
    const unsigned int u2 = xnew8[(size_t)adj[i + 2] * 64 + lane];
    const unsigned int u3 = xnew8[(size_t)adj[i + 3] * 64 + lane];
    const f32x2 v0 = __builtin_amdgcn_cvt_pk_f32_fp8(u0, false);
    const f32x2 v1 = __builtin_amdgcn_cvt_pk_f32_fp8(u1, false);
    const f32x2 v2 = __builtin_amdgcn_cvt_pk_f32_fp8(u2, false);
    const f32x2 v3 = __builtin_amdgcn_cvt_pk_f32_fp8(u3, false);
    const float d0x = mx - v0[0], d0y = my - v0[1];
    const float d1x = mx - v1[0], d1y = my - v1[1];
    const float d2x = mx - v2[0], d2y = my - v2[1];
    const float d3x = mx - v3[0], d3y = my - v3[1];
    s0 += d0x * d0x + d0y * d0y;
    s1 += d1x * d1x + d1y * d1y;
    s2 += d2x * d2x + d2y * d2y;
    s3 += d3x * d3x + d3y * d3y;
  }
  for (; i < end; ++i) {
    const unsigned int u0 = xnew8[(size_t)adj[i] * 64 + lane];
    const f32x2 v0 = __builtin_amdgcn_cvt_pk_f32_fp8(u0, false);
    const float d0x = mx - v0[0], d0y = my - v0[1];
    s0 += d0x * d0x + d0y * d0y;
  }
  float s = (s0 + s1) + (s2 + s3);
  s += __shfl_xor(s, 1);
  s += __shfl_xor(s, 2);
  s += __shfl_xor(s, 4);
  s += __shfl_xor(s, 8);
  s += __shfl_xor(s, 16);
  s += __shfl_xor(s, 32);
  const float tau = tanhf(s / ((float)cnt + 1e-10f));

  const unsigned int xp = x[(size_t)n * 64 + lane];
  const float nx = (1.f - tau) * blo(xp) + tau * mx;
  const float ny = (1.f - tau) * bhi(xp) + tau * my;
  x[(size_t)n * 64 + lane] = (unsigned)f2b(nx) | ((unsigned)f2b(ny) << 16);
}

// ---------------------------------------------------------------------------
extern "C" void kernel_launch(void* const* d_in, const int* in_sizes, int n_in,
                              void* d_out, int out_size, void* d_ws,
                              size_t ws_size, hipStream_t stream) {
  const float* x_in = (const float*)d_in[0];
  const int* ei = (const int*)d_in[1];
  const float* W_in = (const float*)d_in[2];
  const float* W_convs = (const float*)d_in[3];
  const float* b_convs = (const float*)d_in[4];
  const float* W_fc = (const float*)d_in[5];
  const float* b_fc = (const float*)d_in[6];
  float* out = (float*)d_out;

  const int* row = ei;
  const int* col = ei + N_EDGES;

  // Workspace layout
  const size_t PF = (size_t)M_PAD * HID;              // 12,804,096 elements
  unsigned short* xb2 = (unsigned short*)d_ws;        // PF bf16 (current x)
  unsigned short* hb = xb2 + PF;                      // PF bf16
  unsigned short* xnewb = hb + PF;                    // PF bf16
  unsigned short* xnew8 = xnewb + PF;                 // N*64 ushort (fp8x2)
  unsigned short* h8 = xnew8 + (size_t)N_NODES * 64;  // N*64 ushort (int8x2)
  float* scl = (float*)(h8 + (size_t)N_NODES * 64);   // N f32
  unsigned short* wt = (unsigned short*)(scl + N_NODES);  // 73,728 bf16
  int* counts = (int*)(wt + 73728);                   // 2N
  int* incl = counts + SCAN_N;                        // 2N
  int* bsum = incl + SCAN_N;                          // 1024
  int2* seg = (int2*)(bsum + 1024);                   // 2N int2
  unsigned int* ranks = (unsigned int*)(seg + SCAN_N);  // E
  int* adj = (int*)(ranks + N_EDGES);                 // 2E
  unsigned int* adjs = (unsigned int*)(adj + 2 * N_EDGES);  // E (id|scale)
  // total ~ 138 MB

  const int WAVE_BLOCKS = (N_NODES * 64 + 255) / 256;   // 25000

  // ---- weight cast/transpose ----
  cast_w_kernel<<<576, 128, 0, stream>>>(W_in, W_convs, W_fc, wt);

  // ---- CSR build (structure only; lean kernels for max occupancy) ----
  hipMemsetAsync(counts, 0, SCAN_N * sizeof(int), stream);
  count_kernel<<<EDGE_BLOCKS, 256, 0, stream>>>(row, col, counts, ranks);
  scan1_kernel<<<SCAN_NB, SCAN_B, 0, stream>>>(counts, incl, bsum);
  scan2_kernel<<<1, 256, 0, stream>>>(bsum);
  scan3_kernel<<<SCAN_NB, SCAN_B, 0, stream>>>(counts, incl, bsum, seg);
  fill_kernel<<<PAIR_BLOCKS, 256, 0, stream>>>(row, col, ranks, seg, adj);

  // ---- input fc: xb2 = bf16(x_in @ W_in), direct f32 A read ----
  gemm_mfma_kernel<0><<<GEMM_BLOCKS, 256, 0, stream>>>(
      x_in, nullptr, wt, nullptr, nullptr, xb2);

  for (int l = 0; l < NLAYERS; ++l) {
    const float* bl = b_convs + (size_t)l * HID;

    // h = x @ W_convs[l]  (bf16)
    gemm_mfma_kernel<1><<<GEMM_BLOCKS, 256, 0, stream>>>(
        nullptr, xb2, wt + 16384 * (1 + l), nullptr, nullptr, hb);
    // int8 row-scaled quantization of h
    quant_h_kernel<<<WAVE_BLOCKS, 256, 0, stream>>>(
        (const unsigned int*)hb, h8, scl);
    // pack id+scale per agg edge (isolated L2-hot random reads)
    edge_scl_kernel<<<EDGE_BLOCKS, 256, 0, stream>>>(
        adj + N_EDGES, scl, adjs);
    // xnew = relu(segment_sum + b); emits bf16 + fp8
    aggregate_kernel<<<WAVE_BLOCKS, 256, 0, stream>>>(
        h8, adjs, seg, bl, (unsigned int*)xnewb, xnew8);
    // tau + gated update of x (bf16)
    tau_update_kernel<<<WAVE_BLOCKS, 256, 0, stream>>>(
        (const unsigned int*)xnewb, xnew8, seg, adj, (unsigned int*)xb2);
  }

  gemm_mfma_kernel<2><<<GEMM_BLOCKS, 256, 0, stream>>>(
      nullptr, xb2, wt + 65536, b_fc, out, nullptr);
}

// Round 13
// 811.993 us; speedup vs baseline: 1.0522x; 1.0522x over previous
//
#include <hip/hip_runtime.h>
#include <hip/hip_bf16.h>

// Problem constants (from reference)
#define N_NODES 100000
#define N_EDGES 1600000
#define HID 128
#define OUTC 64
#define NLAYERS 3

#define M_PAD 100032            // 64-row-tile padded M (1563 * 64)
#define SCAN_N (2 * N_NODES)    // joint scan over [row_counts | col_counts]
#define SCAN_B 1024
#define SCAN_NB ((SCAN_N + SCAN_B - 1) / SCAN_B)  // 196

#define GEMM_BLOCKS (M_PAD / 64)                  // 1563
#define EDGE_BLOCKS ((N_EDGES + 255) / 256)       // 6250
#define PAIR_BLOCKS ((N_EDGES / 2 + 255) / 256)   // 3125

typedef __attribute__((ext_vector_type(8))) short short8;
typedef __attribute__((ext_vector_type(4))) float f32x4;
typedef __attribute__((ext_vector_type(2))) float f32x2;

__device__ __forceinline__ unsigned short f2b(float f) {
  return __builtin_bit_cast(unsigned short, __float2bfloat16(f));
}
__device__ __forceinline__ float blo(unsigned int u) {  // low bf16 -> f32
  return __builtin_bit_cast(float, u << 16);
}
__device__ __forceinline__ float bhi(unsigned int u) {  // high bf16 -> f32
  return __builtin_bit_cast(float, u & 0xffff0000u);
}

// ---------------------------------------------------------------------------
// Cast + transpose all weights into Wt[n][k] bf16.  All matrices have K=128.
// blocks: [0,128) W_in | [128,512) W_convs | [512,576) W_fc
// ---------------------------------------------------------------------------
__global__ __launch_bounds__(128) void cast_w_kernel(
    const float* __restrict__ W_in, const float* __restrict__ W_convs,
    const float* __restrict__ W_fc, unsigned short* __restrict__ wt) {
  const int b = blockIdx.x;
  const int k = threadIdx.x;
  const float* src;
  unsigned short* dst;
  int n, N;
  if (b < 128) {
    n = b; N = 128; src = W_in; dst = wt + n * 128;
  } else if (b < 512) {
    const int l = (b - 128) >> 7;
    n = (b - 128) & 127; N = 128;
    src = W_convs + (size_t)l * 16384;
    dst = wt + 16384 * (1 + l) + n * 128;
  } else {
    n = b - 512; N = 64; src = W_fc; dst = wt + 65536 + n * 128;
  }
  dst[k] = f2b(src[k * N + n]);
}

// ---------------------------------------------------------------------------
// MFMA GEMM: Y[m][n] = sum_k A[m][k] * Wt[n][k]  (K=128, bf16 MFMA, f32 acc)
// Block = 4 waves x 16 rows = 64 rows; each wave owns COMPLETE output rows.
// MODE 0: A = f32 src (row-guarded, in-reg cast); write bf16 Yb (N=128)
// MODE 1: A = bf16 Xb; epilogue QUANTIZES rows from f32 acc -> int8 H8 +
//         per-row scale Scl (replaces the separate quant_h pass)   (N=128)
// MODE 2: A = bf16 Xb; write f32 Y + bias, row-guarded (N=64)  [final fc]
// ---------------------------------------------------------------------------
template <int MODE>
__global__ __launch_bounds__(256) void gemm_mfma_kernel(
    const float* __restrict__ Xf, const unsigned short* __restrict__ Xb,
    const unsigned short* __restrict__ Wt, const float* __restrict__ bias,
    float* __restrict__ Y, unsigned short* __restrict__ Yb,
    unsigned char* __restrict__ H8, float* __restrict__ Scl) {
  constexpr int NT = (MODE == 2) ? 4 : 8;  // n-tiles of 16
  const int wave = threadIdx.x >> 6;
  const int lane = threadIdx.x & 63;
  const int row0 = blockIdx.x * 64 + wave * 16;
  const int lm = lane & 15;        // m (A) / n (B) index within tile
  const int lk = (lane >> 4) * 8;  // k-group offset

  f32x4 acc[NT];
#pragma unroll
  for (int t = 0; t < NT; ++t) acc[t] = {0.f, 0.f, 0.f, 0.f};

  const int arow = row0 + lm;
#pragma unroll
  for (int ki = 0; ki < 4; ++ki) {
    short8 a;
    if (MODE == 0) {
      float av[8];
      const bool ok = arow < N_NODES;
#pragma unroll
      for (int j = 0; j < 8; ++j)
        av[j] = ok ? Xf[(size_t)arow * 128 + ki * 32 + lk + j] : 0.f;
#pragma unroll
      for (int j = 0; j < 8; ++j)
        a[j] = (short)f2b(av[j]);
    } else {
      a = *reinterpret_cast<const short8*>(Xb + (size_t)arow * 128 + ki * 32 + lk);
    }
#pragma unroll
    for (int t = 0; t < NT; ++t) {
      const short8 b =
          *reinterpret_cast<const short8*>(Wt + (t * 16 + lm) * 128 + ki * 32 + lk);
      acc[t] = __builtin_amdgcn_mfma_f32_16x16x32_bf16(a, b, acc[t], 0, 0, 0);
    }
  }

  if (MODE == 1) {
    // ---- fused int8 row quantization from f32 accumulators ----
    // Row rr = row0 + q*4 + r lives in the 16 lanes sharing q = lane>>4;
    // each lane holds 8 values of that row (cols t*16+lm).
#pragma unroll
    for (int r = 0; r < 4; ++r) {
      float m = 0.f;
#pragma unroll
      for (int t = 0; t < NT; ++t) m = fmaxf(m, fabsf(acc[t][r]));
      m = fmaxf(m, __shfl_xor(m, 1));
      m = fmaxf(m, __shfl_xor(m, 2));
      m = fmaxf(m, __shfl_xor(m, 4));
      m = fmaxf(m, __shfl_xor(m, 8));
      const float inv = (m > 0.f) ? 127.0f / m : 0.f;
      const int rr = row0 + (lane >> 4) * 4 + r;
#pragma unroll
      for (int t = 0; t < NT; ++t) {
        const int q = __float2int_rn(acc[t][r] * inv);
        H8[(size_t)rr * 128 + t * 16 + lm] = (unsigned char)(q & 0xff);
      }
      if (lm == 0) Scl[rr] = m * (1.0f / 127.0f);
    }
    return;
  }

  const int orow = row0 + (lane >> 4) * 4;  // + r
#pragma unroll
  for (int t = 0; t < NT; ++t) {
#pragma unroll
    for (int r = 0; r < 4; ++r) {
      const int rr = orow + r;
      const int cc = t * 16 + lm;
      const float v = acc[t][r];
      if (MODE == 2) {
        if (rr < N_NODES) Y[(size_t)rr * OUTC + cc] = v + bias[cc];
      } else {
        Yb[(size_t)rr * 128 + cc] = f2b(v);
      }
    }
  }
}

// ---------------------------------------------------------------------------
// CSR build step 1: per-node degree counts + per-edge ranks.  Lean kernel
// (4 VGPR, max occupancy) — atomic-latency-bound, do NOT fuse compute in.
// ---------------------------------------------------------------------------
__global__ __launch_bounds__(256) void count_kernel(
    const int* __restrict__ row, const int* __restrict__ col,
    int* __restrict__ counts, unsigned int* __restrict__ ranks) {
  const int e = blockIdx.x * 256 + threadIdx.x;
  if (e >= N_EDGES) return;
  const int pr = atomicAdd(counts + row[e], 1);
  const int pc = atomicAdd(counts + N_NODES + col[e], 1);
  ranks[e] = (unsigned)pr | ((unsigned)pc << 16);
}

__global__ __launch_bounds__(SCAN_B) void scan1_kernel(
    const int* __restrict__ counts, int* __restrict__ incl,
    int* __restrict__ bsum) {
  __shared__ int tmp[SCAN_B];
  const int i = blockIdx.x * SCAN_B + threadIdx.x;
  tmp[threadIdx.x] = (i < SCAN_N) ? counts[i] : 0;
  __syncthreads();
  for (int d = 1; d < SCAN_B; d <<= 1) {
    int t = (threadIdx.x >= d) ? tmp[threadIdx.x - d] : 0;
    __syncthreads();
    tmp[threadIdx.x] += t;
    __syncthreads();
  }
  if (i < SCAN_N) incl[i] = tmp[threadIdx.x];
  if (threadIdx.x == SCAN_B - 1) bsum[blockIdx.x] = tmp[SCAN_B - 1];
}

__global__ __launch_bounds__(256) void scan2_kernel(int* __restrict__ bsum) {
  __shared__ int tmp[256];
  tmp[threadIdx.x] = (threadIdx.x < SCAN_NB) ? bsum[threadIdx.x] : 0;
  __syncthreads();
  for (int d = 1; d < 256; d <<= 1) {
    int t = (threadIdx.x >= d) ? tmp[threadIdx.x - d] : 0;
    __syncthreads();
    tmp[threadIdx.x] += t;
    __syncthreads();
  }
  if (threadIdx.x < SCAN_NB) bsum[threadIdx.x] = tmp[threadIdx.x];
}

// Scan step C: seg[i] = {exclusive start, count} (int2, one 8B load for users)
__global__ __launch_bounds__(SCAN_B) void scan3_kernel(
    const int* __restrict__ counts, const int* __restrict__ incl,
    const int* __restrict__ bsum, int2* __restrict__ seg) {
  const int i = blockIdx.x * SCAN_B + threadIdx.x;
  if (i >= SCAN_N) return;
  const int c = counts[i];
  const int v = incl[i] + (blockIdx.x > 0 ? bsum[blockIdx.x - 1] : 0);
  seg[i] = make_int2(v - c, c);
}

// ---------------------------------------------------------------------------
// CSR build step 2: fill adjacency — atomic-free; 2 edges per thread.
// adj[pos in [0,E)]   = col[e]  (neighbors of row-node, for tau)
// adj[pos in [E,2E)]  = row[e]  (sources of col-node, for aggregation)
// ---------------------------------------------------------------------------
__global__ __launch_bounds__(256) void fill_kernel(
    const int* __restrict__ row, const int* __restrict__ col,
    const unsigned int* __restrict__ ranks, const int2* __restrict__ seg,
    int* __restrict__ adj) {
  const int p = blockIdx.x * 256 + threadIdx.x;  // pair index
  if (p * 2 >= N_EDGES) return;
  const int2 r2 = reinterpret_cast<const int2*>(row)[p];
  const int2 c2 = reinterpret_cast<const int2*>(col)[p];
  const uint2 u2 = reinterpret_cast<const uint2*>(ranks)[p];
  adj[seg[r2.x].x + (int)(u2.x & 0xffffu)] = c2.x;
  adj[seg[N_NODES + c2.x].x + (int)(u2.x >> 16)] = r2.x;
  adj[seg[r2.y].x + (int)(u2.y & 0xffffu)] = c2.y;
  adj[seg[N_NODES + c2.y].x + (int)(u2.y >> 16)] = r2.y;
}

// ---------------------------------------------------------------------------
// Pack source-id + bf16(scale) into one word per agg edge:
//   adjs[i] = src | (bf16_bits(scl[src]) << 17)    (src < 2^17, scale >= 0)
// Isolated kernel: the random scl reads hit a 400 KB L2-hot array; aggregate
// then needs NO separate per-edge scale access (saves 1 L3 sector per edge).
// ---------------------------------------------------------------------------
__global__ __launch_bounds__(256) void edge_scl_kernel(
    const int* __restrict__ adj_agg, const float* __restrict__ scl,
    unsigned int* __restrict__ adjs) {
  const int i = blockIdx.x * 256 + threadIdx.x;
  if (i >= N_EDGES) return;
  const int id = adj_agg[i];
  const unsigned int sb = (unsigned int)f2b(scl[id]);  // sign bit = 0
  adjs[i] = (unsigned int)id | (sb << 17);
}

// ---------------------------------------------------------------------------
// Aggregate (gather, int8 + packed scale):
//   xnew[n] = relu(sum_{e: col=n} scl[s]*h8[s] + b)
// One wave per node; lane holds dims [2l, 2l+1].  One coalesced adjs word
// per edge carries id+scale; gather is a 128B int8 row (2 sectors).
// Writes bf16 (gate / next GEMM) AND fp8 e4m3 (tau neighbor gather).
// ---------------------------------------------------------------------------
__global__ __launch_bounds__(256) void aggregate_kernel(
    const unsigned short* __restrict__ h8, const unsigned int* __restrict__ adjs,
    const int2* __restrict__ seg, const float* __restrict__ b,
    unsigned int* __restrict__ xnewb, unsigned short* __restrict__ xnew8) {
  const int g = blockIdx.x * 256 + threadIdx.x;
  const int n = g >> 6;
  if (n >= N_NODES) return;
  const int lane = g & 63;
  const int2 sg = seg[N_NODES + n];
  const int start = sg.x - N_EDGES;  // agg segment positions live in [E,2E)
  const int end = start + sg.y;

  float ax[8], ay[8];
#pragma unroll
  for (int j = 0; j < 8; ++j) { ax[j] = 0.f; ay[j] = 0.f; }
  int i = start;
  for (; i + 7 < end; i += 8) {
    unsigned int w[8];
    unsigned int u[8];
#pragma unroll
    for (int j = 0; j < 8; ++j) w[j] = adjs[i + j];
#pragma unroll
    for (int j = 0; j < 8; ++j)
      u[j] = h8[(size_t)(w[j] & 0x1ffffu) * 64 + lane];
#pragma unroll
    for (int j = 0; j < 8; ++j) {
      const float s = __builtin_bit_cast(float, (w[j] & 0xfffe0000u) >> 1);
      ax[j] += (float)(int)(signed char)(u[j] & 0xff) * s;
      ay[j] += (float)((int)(short)(unsigned short)u[j] >> 8) * s;
    }
  }
  for (; i < end; ++i) {
    const unsigned int w0 = adjs[i];
    const unsigned int u0 = h8[(size_t)(w0 & 0x1ffffu) * 64 + lane];
    const float s0 = __builtin_bit_cast(float, (w0 & 0xfffe0000u) >> 1);
    ax[0] += (float)(int)(signed char)(u0 & 0xff) * s0;
    ay[0] += (float)((int)(short)(unsigned short)u0 >> 8) * s0;
  }
#pragma unroll
  for (int j = 4; j < 8; ++j) { ax[j - 4] += ax[j]; ay[j - 4] += ay[j]; }
  const float2 bb = *reinterpret_cast<const float2*>(b + lane * 2);
  const float ox = fmaxf(((ax[0] + ax[1]) + (ax[2] + ax[3])) + bb.x, 0.f);
  const float oy = fmaxf(((ay[0] + ay[1]) + (ay[2] + ay[3])) + bb.y, 0.f);
  xnewb[(size_t)n * 64 + lane] = (unsigned)f2b(ox) | ((unsigned)f2b(oy) << 16);
  const unsigned int p8 = __builtin_amdgcn_cvt_pk_fp8_f32(ox, oy, 0u, false);
  xnew8[(size_t)n * 64 + lane] = (unsigned short)(p8 & 0xffffu);
}

// ---------------------------------------------------------------------------
// Tau + gated update, fused.  Neighbor rows gathered as fp8 e4m3 (tau is
// tanh-saturated -> quantization noise is annihilated).  One wave per node:
//   s   = sum_{e: row=n} ||xnew[n] - xnew[col[e]]||^2
//   tau = tanh(s / (deg + 1e-10))
//   x[n] = (1-tau)*x[n] + tau*xnew[n]   (bf16 x)
// ---------------------------------------------------------------------------
__global__ __launch_bounds__(256) void tau_update_kernel(
    const unsigned int* __restrict__ xnewb, const unsigned short* __restrict__ xnew8,
    const int2* __restrict__ seg, const int* __restrict__ adj,
    unsigned int* __restrict__ x) {
  const int g = blockIdx.x * 256 + threadIdx.x;
  const int n = g >> 6;
  if (n >= N_NODES) return;
  const int lane = g & 63;
  const int2 sg = seg[n];
  const int start = sg.x;
  const int cnt = sg.y;
  const int end = start + cnt;

  const unsigned int mp = xnewb[(size_t)n * 64 + lane];
  const float mx = blo(mp), my = bhi(mp);

  float s0 = 0.f, s1 = 0.f, s2 = 0.f, s3 = 0.f;
  int i = start;
  for (; i + 3 < end; i += 4) {
    const unsigned int u0 = xnew8[(size_t)adj[i] * 64 + lane];
    const unsigned int u1 = xnew8[(size_t)adj[i + 1] * 64 + lane];
    const unsigned int u2 = xnew8[(size_t)adj[i + 2] * 64 + lane];
    const unsigned int u3 = xnew8[(size_t)adj[i + 3] * 64 + lane];
    const f32x2 v0 = __builtin_amdgcn_cvt_pk_f32_fp8(u0, false);
    const f32x2 v1 = __builtin_amdgcn_cvt_pk_f32_fp8(u1, false);
    const f32x2 v2 = __builtin_amdgcn_cvt_pk_f32_fp8(u2, false);
    const f32x2 v3 = __builtin_amdgcn_cvt_pk_f32_fp8(u3, false);
    const float d0x = mx - v0[0], d0y = my - v0[1];
    const float d1x = mx - v1[0], d1y = my - v1[1];
    const float d2x = mx - v2[0], d2y = my - v2[1];
    const float d3x = mx - v3[0], d3y = my - v3[1];
    s0 += d0x * d0x + d0y * d0y;
    s1 += d1x * d1x + d1y * d1y;
    s2 += d2x * d2x + d2y * d2y;
    s3 += d3x * d3x + d3y * d3y;
  }
  for (; i < end; ++i) {
    const unsigned int u0 = xnew8[(size_t)adj[i] * 64 + lane];
    const f32x2 v0 = __builtin_amdgcn_cvt_pk_f32_fp8(u0, false);
    const float d0x = mx - v0[0], d0y = my - v0[1];
    s0 += d0x * d0x + d0y * d0y;
  }
  float s = (s0 + s1) + (s2 + s3);
  s += __shfl_xor(s, 1);
  s += __shfl_xor(s, 2);
  s += __shfl_xor(s, 4);
  s += __shfl_xor(s, 8);
  s += __shfl_xor(s, 16);
  s += __shfl_xor(s, 32);
  const float tau = tanhf(s / ((float)cnt + 1e-10f));

  const unsigned int xp = x[(size_t)n * 64 + lane];
  const float nx = (1.f - tau) * blo(xp) + tau * mx;
  const float ny = (1.f - tau) * bhi(xp) + tau * my;
  x[(size_t)n * 64 + lane] = (unsigned)f2b(nx) | ((unsigned)f2b(ny) << 16);
}

// ---------------------------------------------------------------------------
extern "C" void kernel_launch(void* const* d_in, const int* in_sizes, int n_in,
                              void* d_out, int out_size, void* d_ws,
                              size_t ws_size, hipStream_t stream) {
  const float* x_in = (const float*)d_in[0];
  const int* ei = (const int*)d_in[1];
  const float* W_in = (const float*)d_in[2];
  const float* W_convs = (const float*)d_in[3];
  const float* b_convs = (const float*)d_in[4];
  const float* W_fc = (const float*)d_in[5];
  const float* b_fc = (const float*)d_in[6];
  float* out = (float*)d_out;

  const int* row = ei;
  const int* col = ei + N_EDGES;

  // Workspace layout
  const size_t PF = (size_t)M_PAD * HID;              // 12,804,096 elements
  unsigned short* xb2 = (unsigned short*)d_ws;        // PF bf16 (current x)
  unsigned short* xnewb = xb2 + PF;                   // PF bf16
  unsigned short* xnew8 = xnewb + PF;                 // N*64 ushort (fp8x2)
  unsigned short* h8 = xnew8 + (size_t)N_NODES * 64;  // M_PAD*64 ushort (int8x2)
  float* scl = (float*)(h8 + (size_t)M_PAD * 64);     // M_PAD f32
  unsigned short* wt = (unsigned short*)(scl + M_PAD);  // 73,728 bf16
  int* counts = (int*)(wt + 73728);                   // 2N
  int* incl = counts + SCAN_N;                        // 2N
  int* bsum = incl + SCAN_N;                          // 1024
  int2* seg = (int2*)(bsum + 1024);                   // 2N int2
  unsigned int* ranks = (unsigned int*)(seg + SCAN_N);  // E
  int* adj = (int*)(ranks + N_EDGES);                 // 2E
  unsigned int* adjs = (unsigned int*)(adj + 2 * N_EDGES);  // E (id|scale)
  // total ~ 113 MB

  const int WAVE_BLOCKS = (N_NODES * 64 + 255) / 256;   // 25000

  // ---- weight cast/transpose ----
  cast_w_kernel<<<576, 128, 0, stream>>>(W_in, W_convs, W_fc, wt);

  // ---- CSR build (structure only; lean kernels for max occupancy) ----
  hipMemsetAsync(counts, 0, SCAN_N * sizeof(int), stream);
  count_kernel<<<EDGE_BLOCKS, 256, 0, stream>>>(row, col, counts, ranks);
  scan1_kernel<<<SCAN_NB, SCAN_B, 0, stream>>>(counts, incl, bsum);
  scan2_kernel<<<1, 256, 0, stream>>>(bsum);
  scan3_kernel<<<SCAN_NB, SCAN_B, 0, stream>>>(counts, incl, bsum, seg);
  fill_kernel<<<PAIR_BLOCKS, 256, 0, stream>>>(row, col, ranks, seg, adj);

  // ---- input fc: xb2 = bf16(x_in @ W_in), direct f32 A read ----
  gemm_mfma_kernel<0><<<GEMM_BLOCKS, 256, 0, stream>>>(
      x_in, nullptr, wt, nullptr, nullptr, xb2, nullptr, nullptr);

  for (int l = 0; l < NLAYERS; ++l) {
    const float* bl = b_convs + (size_t)l * HID;

    // h = x @ W_convs[l] -> int8 h8 + per-row scl, quantized in-epilogue
    gemm_mfma_kernel<1><<<GEMM_BLOCKS, 256, 0, stream>>>(
        nullptr, xb2, wt + 16384 * (1 + l), nullptr, nullptr, nullptr,
        (unsigned char*)h8, scl);
    // pack id+scale per agg edge (isolated L2-hot random reads)
    edge_scl_kernel<<<EDGE_BLOCKS, 256, 0, stream>>>(
        adj + N_EDGES, scl, adjs);
    // xnew = relu(segment_sum + b); emits bf16 + fp8
    aggregate_kernel<<<WAVE_BLOCKS, 256, 0, stream>>>(
        h8, adjs, seg, bl, (unsigned int*)xnewb, xnew8);
    // tau + gated update of x (bf16)
    tau_update_kernel<<<WAVE_BLOCKS, 256, 0, stream>>>(
        (const unsigned int*)xnewb, xnew8, seg, adj, (unsigned int*)xb2);
  }

  gemm_mfma_kernel<2><<<GEMM_BLOCKS, 256, 0, stream>>>(
      nullptr, xb2, wt + 65536, b_fc, out, nullptr, nullptr, nullptr);
}